// Round 7
// baseline (11871.059 us; speedup 1.0000x reference)
//
#include <hip/hip_runtime.h>
#include <cmath>

#define TOK 4608      // B*N
#define DMODEL 768

typedef __attribute__((ext_vector_type(8))) _Float16 f16x8;
typedef __attribute__((ext_vector_type(4))) float f32x4;
typedef unsigned short ushort_t;

__device__ __forceinline__ float gelu_exact(float x) {
    return 0.5f * x * (1.0f + erff(x * 0.70710678118654752440f));
}

// 2-limb fp16 decomposition, RN both limbs. x = h + m/2048 + delta, |delta| <= 2^-22 |x|.
// m is pre-scaled by 2048 so it is never subnormal (robust to MFMA input-denorm flush).
__device__ __forceinline__ void cvt2(float x, unsigned short& h, unsigned short& m)
{
    _Float16 hf = (_Float16)x;                  // v_cvt_f16_f32 (RN)
    float r = (x - (float)hf) * 2048.0f;        // exact residual (Sterbenz), rescaled
    _Float16 mf = (_Float16)r;
    h = __builtin_bit_cast(unsigned short, hf);
    m = __builtin_bit_cast(unsigned short, mf);
}

__device__ __forceinline__ float tof(unsigned short u) {
    return (float)__builtin_bit_cast(_Float16, u);
}

// ---------------- fp32 -> limb planes (weights, once per layer) ----------------
__global__ __launch_bounds__(256)
void cvt_plane(const float* __restrict__ src, ushort_t* __restrict__ dh,
               ushort_t* __restrict__ dm, int n)
{
    int i = (blockIdx.x*256 + threadIdx.x) << 2;
    if (i >= n) return;
    float4 v = *(const float4*)(src + i);
    ushort4 H, M;
    cvt2(v.x, H.x, M.x); cvt2(v.y, H.y, M.y);
    cvt2(v.z, H.z, M.z); cvt2(v.w, H.w, M.w);
    *(ushort4*)(dh + i) = H;
    *(ushort4*)(dm + i) = M;
}

// ---------------- im2col -> limb planes ----------------
__global__ __launch_bounds__(256)
void im2col_kernel(const float* __restrict__ x, ushort_t* __restrict__ ph,
                   ushort_t* __restrict__ pm)
{
    int idx = blockIdx.x*256 + threadIdx.x;   // tokid*256 + k
    int k = idx & 255, tokid = idx >> 8;
    int b = tokid / 576, n = tokid % 576;
    int hp = n / 24, wp = n % 24;
    float v = x[(size_t)b*147456 + (size_t)(hp*16 + (k >> 4))*384 + wp*16 + (k & 15)];
    unsigned short hh, mm;
    cvt2(v, hh, mm);
    ph[idx] = hh; pm[idx] = mm;
}

// ---------------- LayerNorm over D=768 -> limb planes ----------------
__global__ __launch_bounds__(256)
void ln_kernel(const float* __restrict__ in, ushort_t* __restrict__ outh,
               ushort_t* __restrict__ outm,
               const float* __restrict__ g, const float* __restrict__ bta)
{
    int tokid = blockIdx.x;
    const float* xr = in + (size_t)tokid*768;
    int t = threadIdx.x;
    float v0 = xr[t], v1 = xr[t+256], v2 = xr[t+512];
    float s = v0+v1+v2, q = v0*v0+v1*v1+v2*v2;
    for (int off = 32; off > 0; off >>= 1) {
        s += __shfl_down(s, off);
        q += __shfl_down(q, off);
    }
    __shared__ float ss[4], sq[4];
    int wv = t >> 6, ln = t & 63;
    if (ln == 0) { ss[wv] = s; sq[wv] = q; }
    __syncthreads();
    float ts = ss[0]+ss[1]+ss[2]+ss[3];
    float tq = sq[0]+sq[1]+sq[2]+sq[3];
    float mean = ts * (1.f/768.f);
    float var  = tq * (1.f/768.f) - mean*mean;
    float inv  = rsqrtf(var + 1e-5f);
    size_t base = (size_t)tokid*768;
    unsigned short hh, mm;
    float y0 = (v0-mean)*inv*g[t]     + bta[t];
    float y1 = (v1-mean)*inv*g[t+256] + bta[t+256];
    float y2 = (v2-mean)*inv*g[t+512] + bta[t+512];
    cvt2(y0, hh, mm); outh[base+t]     = hh; outm[base+t]     = mm;
    cvt2(y1, hh, mm); outh[base+t+256] = hh; outm[base+t+256] = mm;
    cvt2(y2, hh, mm); outh[base+t+512] = hh; outm[base+t+512] = mm;
}

// ---------------- MFMA NT GEMM on limb planes ----------------
// A, B pre-decomposed into h/m ushort planes; staging = pure uint4 copies (no VALU cvt).
// 3 MFMA terms: hh -> acc1, hm+mh -> acc2; val = acc1 + acc2/2048.
// 128x128 tile, BK=32, 4 waves (2x2), each wave 64x64 = 4x4 frags of 16x16x32.
// mode 0: Ch/Cm = limbs(val)          1: C += val (fp32)
// mode 2: Ch/Cm[gather] = limbs(gelu(val))   3: C[gather] += wgt*val (fp32)
// mode 4: C = val + pos[(row%576)*768+n]  (wgt doubles as pos pointer)
__global__ __launch_bounds__(256, 2)
void gemm_mfma(const ushort_t* __restrict__ Ahp, const ushort_t* __restrict__ Amp,
               const ushort_t* __restrict__ Bhp, const ushort_t* __restrict__ Bmp,
               const float* __restrict__ bias, float* __restrict__ C,
               ushort_t* __restrict__ Chp, ushort_t* __restrict__ Cmp,
               int M, int Nout, int K, int ldA, int ldC, int mode,
               const int* __restrict__ lists, const int* __restrict__ counts,
               const float* __restrict__ wgt)
{
    int Meff = M;
    const int* gather = nullptr;
    if (counts) {
        int e = blockIdx.z;
        Meff   = counts[e];
        gather = lists + e * TOK;
        Bhp   += (size_t)e * Nout * K;
        Bmp   += (size_t)e * Nout * K;
        bias  += (size_t)e * Nout;
    }
    int m0 = blockIdx.y << 7, n0 = blockIdx.x << 7;
    if (m0 >= Meff) return;

    __shared__ unsigned short Ah[128][40];
    __shared__ unsigned short Am[128][40];
    __shared__ unsigned short Bh[128][40];
    __shared__ unsigned short Bm[128][40];

    int t = threadIdx.x;
    int srow = t >> 1;               // staging row 0..127
    int koff = (t & 1) << 4;         // k-offset 0 or 16

    int ar = m0 + srow;
    long agrow = -1;
    if (ar < Meff) agrow = gather ? gather[ar] : ar;
    const ushort_t* Ah_src = (agrow >= 0) ? (Ahp + (size_t)agrow*ldA + koff) : nullptr;
    const ushort_t* Am_src = (agrow >= 0) ? (Amp + (size_t)agrow*ldA + koff) : nullptr;
    const ushort_t* Bh_src = Bhp + (size_t)(n0 + srow)*K + koff;
    const ushort_t* Bm_src = Bmp + (size_t)(n0 + srow)*K + koff;

    int lane = t & 63;
    int wv   = t >> 6;
    int wm   = (wv >> 1) << 6;
    int wn   = (wv & 1) << 6;
    int r16  = lane & 15;
    int g    = lane >> 4;

    f32x4 acc1[4][4], acc2[4][4];
    #pragma unroll
    for (int i = 0; i < 4; ++i)
        #pragma unroll
        for (int j = 0; j < 4; ++j) {
            acc1[i][j] = (f32x4){0.f, 0.f, 0.f, 0.f};
            acc2[i][j] = (f32x4){0.f, 0.f, 0.f, 0.f};
        }

    uint4 rah[2], ram[2], rbh[2], rbm[2];
    rah[0] = rah[1] = ram[0] = ram[1] = (uint4){0u,0u,0u,0u};

    auto load_tile = [&](int k0) {
        if (Ah_src) {
            rah[0] = *(const uint4*)(Ah_src + k0);
            rah[1] = *(const uint4*)(Ah_src + k0 + 8);
            ram[0] = *(const uint4*)(Am_src + k0);
            ram[1] = *(const uint4*)(Am_src + k0 + 8);
        }
        rbh[0] = *(const uint4*)(Bh_src + k0);
        rbh[1] = *(const uint4*)(Bh_src + k0 + 8);
        rbm[0] = *(const uint4*)(Bm_src + k0);
        rbm[1] = *(const uint4*)(Bm_src + k0 + 8);
    };

    load_tile(0);

    for (int k0 = 0; k0 < K; k0 += 32) {
        __syncthreads();
        *(uint4*)&Ah[srow][koff]   = rah[0];
        *(uint4*)&Ah[srow][koff+8] = rah[1];
        *(uint4*)&Am[srow][koff]   = ram[0];
        *(uint4*)&Am[srow][koff+8] = ram[1];
        *(uint4*)&Bh[srow][koff]   = rbh[0];
        *(uint4*)&Bh[srow][koff+8] = rbh[1];
        *(uint4*)&Bm[srow][koff]   = rbm[0];
        *(uint4*)&Bm[srow][koff+8] = rbm[1];
        __syncthreads();
        if (k0 + 32 < K) load_tile(k0 + 32);   // prefetch hides under MFMA

        f16x8 fah[4], fam[4];
        #pragma unroll
        for (int i = 0; i < 4; ++i) {
            int ml = wm + i*16 + r16;
            fah[i] = *(const f16x8*)&Ah[ml][g*8];
            fam[i] = *(const f16x8*)&Am[ml][g*8];
        }
        #pragma unroll
        for (int j = 0; j < 4; ++j) {
            int nl = wn + j*16 + r16;
            f16x8 fbh = *(const f16x8*)&Bh[nl][g*8];
            f16x8 fbm = *(const f16x8*)&Bm[nl][g*8];
            #pragma unroll
            for (int i = 0; i < 4; ++i) {
                acc1[i][j] = __builtin_amdgcn_mfma_f32_16x16x32_f16(fah[i], fbh, acc1[i][j], 0, 0, 0);
                acc2[i][j] = __builtin_amdgcn_mfma_f32_16x16x32_f16(fah[i], fbm, acc2[i][j], 0, 0, 0);
                acc2[i][j] = __builtin_amdgcn_mfma_f32_16x16x32_f16(fam[i], fbh, acc2[i][j], 0, 0, 0);
            }
        }
    }

    const float MS = 1.0f / 2048.0f;
    float biasv[4];
    #pragma unroll
    for (int j = 0; j < 4; ++j) biasv[j] = bias[n0 + wn + j*16 + r16];

    #pragma unroll
    for (int i = 0; i < 4; ++i) {
        int mb = m0 + wm + i*16 + (g << 2);
        #pragma unroll
        for (int r = 0; r < 4; ++r) {
            int m = mb + r;
            if (m >= Meff) continue;
            int row = gather ? gather[m] : m;
            size_t rowoff = (size_t)row*ldC + n0 + wn + r16;
            float w = (mode == 3) ? wgt[row] : 0.f;
            #pragma unroll
            for (int j = 0; j < 4; ++j) {
                float val = acc1[i][j][r] + acc2[i][j][r] * MS + biasv[j];
                size_t off = rowoff + j*16;
                if (mode == 0) {
                    unsigned short hh, mm;
                    cvt2(val, hh, mm);
                    Chp[off] = hh; Cmp[off] = mm;
                } else if (mode == 1) {
                    C[off] += val;
                } else if (mode == 2) {
                    unsigned short hh, mm;
                    cvt2(gelu_exact(val), hh, mm);
                    Chp[off] = hh; Cmp[off] = mm;
                } else if (mode == 3) {
                    C[off] += w * val;
                } else {
                    C[off] = val + wgt[(size_t)(row % 576)*768 + n0 + wn + j*16 + r16];
                }
            }
        }
    }
}

// ---------------- attention (MFMA flash) on qkv limb planes ----------------
// One block = 64 q-rows x (head, batch), 4 waves x 16 q-rows. Staging = uint copies.
// P limbs derived from fp32 softmax in-kernel. Output written as limb planes.
__global__ __launch_bounds__(256)
void attn_kernel(const ushort_t* __restrict__ qh, const ushort_t* __restrict__ qm,
                 ushort_t* __restrict__ aoh, ushort_t* __restrict__ aom)
{
    int q0 = blockIdx.x << 6;
    int h  = blockIdx.y;
    int b  = blockIdx.z;
    size_t bbase = (size_t)b * 576 * 2304;
    int qoff = h << 6, koff2 = 768 + (h << 6), voff = 1536 + (h << 6);

    __shared__ unsigned short Qh[64][72], Qm[64][72];
    __shared__ unsigned short Kh[64][72], Km[64][72];
    __shared__ unsigned short Vth[64][72], Vtm[64][72];   // transposed: [d][j]
    __shared__ unsigned short Ph[64][72], Pm[64][72];

    int t    = threadIdx.x;
    int lane = t & 63;
    int wq   = t >> 6;
    int l15  = lane & 15;
    int g    = lane >> 4;

    int srow = t >> 2;           // staging row 0..63
    int sq   = t & 3;            // quarter (16 elements)

    // ---- stage Q ----
    {
        const ushort_t* sh = qh + bbase + (size_t)(q0 + srow)*2304 + qoff + (sq << 4);
        const ushort_t* sm = qm + bbase + (size_t)(q0 + srow)*2304 + qoff + (sq << 4);
        *(uint4*)&Qh[srow][(sq<<4)]   = *(const uint4*)(sh);
        *(uint4*)&Qh[srow][(sq<<4)+8] = *(const uint4*)(sh + 8);
        *(uint4*)&Qm[srow][(sq<<4)]   = *(const uint4*)(sm);
        *(uint4*)&Qm[srow][(sq<<4)+8] = *(const uint4*)(sm + 8);
    }
    __syncthreads();

    f16x8 fqh[2], fqm[2];
    #pragma unroll
    for (int ks = 0; ks < 2; ++ks) {
        fqh[ks] = *(const f16x8*)&Qh[wq*16 + l15][ks*32 + g*8];
        fqm[ks] = *(const f16x8*)&Qm[wq*16 + l15][ks*32 + g*8];
    }

    uint4 pkh[2], pkm[2];
    uint2 pvh[4], pvm[4];
    auto fetch_kv = [&](int j0) {
        const ushort_t* kh_ = qh + bbase + (size_t)(j0 + srow)*2304 + koff2 + (sq << 4);
        const ushort_t* km_ = qm + bbase + (size_t)(j0 + srow)*2304 + koff2 + (sq << 4);
        pkh[0] = *(const uint4*)(kh_);     pkh[1] = *(const uint4*)(kh_ + 8);
        pkm[0] = *(const uint4*)(km_);     pkm[1] = *(const uint4*)(km_ + 8);
        const ushort_t* vh_ = qh + bbase + (size_t)(j0 + srow)*2304 + voff + (sq << 2);
        const ushort_t* vm_ = qm + bbase + (size_t)(j0 + srow)*2304 + voff + (sq << 2);
        #pragma unroll
        for (int k = 0; k < 4; ++k) {
            pvh[k] = *(const uint2*)(vh_ + (k << 4));
            pvm[k] = *(const uint2*)(vm_ + (k << 4));
        }
    };
    fetch_kv(0);

    f32x4 o1[4], o2[4];
    #pragma unroll
    for (int df = 0; df < 4; ++df) {
        o1[df] = (f32x4){0.f,0.f,0.f,0.f};
        o2[df] = (f32x4){0.f,0.f,0.f,0.f};
    }
    float m_[4] = {-3.4e38f,-3.4e38f,-3.4e38f,-3.4e38f};
    float l_[4] = {0.f,0.f,0.f,0.f};
    const float MS = 1.0f / 2048.0f;

    for (int j0 = 0; j0 < 576; j0 += 64) {
        __syncthreads();   // previous tile's LDS reads done
        // stage K (natural [j][d])
        *(uint4*)&Kh[srow][(sq<<4)]   = pkh[0];
        *(uint4*)&Kh[srow][(sq<<4)+8] = pkh[1];
        *(uint4*)&Km[srow][(sq<<4)]   = pkm[0];
        *(uint4*)&Km[srow][(sq<<4)+8] = pkm[1];
        // stage V transposed ([d][j])
        #pragma unroll
        for (int k = 0; k < 4; ++k) {
            const ushort_t* ph = (const ushort_t*)&pvh[k];
            const ushort_t* pm = (const ushort_t*)&pvm[k];
            int dbase = (sq << 2) + (k << 4);
            Vth[dbase+0][srow] = ph[0]; Vtm[dbase+0][srow] = pm[0];
            Vth[dbase+1][srow] = ph[1]; Vtm[dbase+1][srow] = pm[1];
            Vth[dbase+2][srow] = ph[2]; Vtm[dbase+2][srow] = pm[2];
            Vth[dbase+3][srow] = ph[3]; Vtm[dbase+3][srow] = pm[3];
        }
        __syncthreads();
        int jn = j0 + 64;
        if (jn < 576) fetch_kv(jn);      // prefetch hides under compute

        // ---- QK^T ----
        f32x4 s1[4], s2[4];
        #pragma unroll
        for (int jf = 0; jf < 4; ++jf) {
            s1[jf] = (f32x4){0.f,0.f,0.f,0.f};
            s2[jf] = (f32x4){0.f,0.f,0.f,0.f};
        }
        #pragma unroll
        for (int jf = 0; jf < 4; ++jf) {
            #pragma unroll
            for (int ks = 0; ks < 2; ++ks) {
                f16x8 fkh = *(const f16x8*)&Kh[jf*16 + l15][ks*32 + g*8];
                f16x8 fkm = *(const f16x8*)&Km[jf*16 + l15][ks*32 + g*8];
                s1[jf] = __builtin_amdgcn_mfma_f32_16x16x32_f16(fqh[ks], fkh, s1[jf], 0, 0, 0);
                s2[jf] = __builtin_amdgcn_mfma_f32_16x16x32_f16(fqh[ks], fkm, s2[jf], 0, 0, 0);
                s2[jf] = __builtin_amdgcn_mfma_f32_16x16x32_f16(fqm[ks], fkh, s2[jf], 0, 0, 0);
            }
        }
        float p[4][4];
        #pragma unroll
        for (int jf = 0; jf < 4; ++jf)
            #pragma unroll
            for (int r = 0; r < 4; ++r)
                p[jf][r] = (s1[jf][r] + s2[jf][r]*MS) * 0.125f;

        // ---- online softmax ----
        #pragma unroll
        for (int r = 0; r < 4; ++r) {
            float tm = fmaxf(fmaxf(p[0][r], p[1][r]), fmaxf(p[2][r], p[3][r]));
            #pragma unroll
            for (int off = 8; off > 0; off >>= 1) tm = fmaxf(tm, __shfl_xor(tm, off, 16));
            float mn = fmaxf(m_[r], tm);
            float f  = expf(m_[r] - mn);
            m_[r] = mn;
            l_[r] *= f;
            #pragma unroll
            for (int df = 0; df < 4; ++df) { o1[df][r] *= f; o2[df][r] *= f; }
            float ps = 0.f;
            #pragma unroll
            for (int jf = 0; jf < 4; ++jf) {
                p[jf][r] = expf(p[jf][r] - mn);
                ps += p[jf][r];
            }
            #pragma unroll
            for (int off = 8; off > 0; off >>= 1) ps += __shfl_xor(ps, off, 16);
            l_[r] += ps;
        }
        // write P limbs (own wave's rows only)
        #pragma unroll
        for (int jf = 0; jf < 4; ++jf)
            #pragma unroll
            for (int r = 0; r < 4; ++r) {
                unsigned short ph, pm;
                cvt2(p[jf][r], ph, pm);
                Ph[wq*16 + g*4 + r][jf*16 + l15] = ph;
                Pm[wq*16 + g*4 + r][jf*16 + l15] = pm;
            }

        // ---- PV ----
        #pragma unroll
        for (int ks = 0; ks < 2; ++ks) {
            f16x8 fph = *(const f16x8*)&Ph[wq*16 + l15][ks*32 + g*8];
            f16x8 fpm = *(const f16x8*)&Pm[wq*16 + l15][ks*32 + g*8];
            #pragma unroll
            for (int df = 0; df < 4; ++df) {
                f16x8 fvh = *(const f16x8*)&Vth[df*16 + l15][ks*32 + g*8];
                f16x8 fvm = *(const f16x8*)&Vtm[df*16 + l15][ks*32 + g*8];
                o1[df] = __builtin_amdgcn_mfma_f32_16x16x32_f16(fph, fvh, o1[df], 0, 0, 0);
                o2[df] = __builtin_amdgcn_mfma_f32_16x16x32_f16(fph, fvm, o2[df], 0, 0, 0);
                o2[df] = __builtin_amdgcn_mfma_f32_16x16x32_f16(fpm, fvh, o2[df], 0, 0, 0);
            }
        }
    }

    // ---- epilogue: limbs((o1 + o2/2048)/l) -> attn planes ----
    #pragma unroll
    for (int r = 0; r < 4; ++r) {
        float inv = 1.f / l_[r];
        size_t rowoff = (size_t)(b*576 + q0 + wq*16 + g*4 + r)*768 + qoff + l15;
        #pragma unroll
        for (int df = 0; df < 4; ++df) {
            float ov = (o1[df][r] + o2[df][r]*MS) * inv;
            unsigned short hh, mm;
            cvt2(ov, hh, mm);
            aoh[rowoff + df*16] = hh;
            aom[rowoff + df*16] = mm;
        }
    }
}

// ---------------- gate: scores from h limb planes -> argmax -> expert lists --------
__global__ __launch_bounds__(256)
void gate_kernel(const ushort_t* __restrict__ hh, const ushort_t* __restrict__ hm,
                 const float* __restrict__ gw, const float* __restrict__ gb,
                 float* __restrict__ wgt, int* __restrict__ lists, int* __restrict__ counts)
{
    int tokid = blockIdx.x;
    int t = threadIdx.x;
    const ushort_t* hrh = hh + (size_t)tokid*768;
    const ushort_t* hrm = hm + (size_t)tokid*768;
    const float MS = 1.0f / 2048.0f;
    float p0=0.f,p1=0.f,p2=0.f,p3=0.f;
    for (int k = t; k < 768; k += 256) {
        float hv = tof(hrh[k]) + tof(hrm[k]) * MS;
        p0 = fmaf(hv, gw[k],        p0);
        p1 = fmaf(hv, gw[768 + k],  p1);
        p2 = fmaf(hv, gw[1536 + k], p2);
        p3 = fmaf(hv, gw[2304 + k], p3);
    }
    for (int off = 32; off > 0; off >>= 1) {
        p0 += __shfl_down(p0, off);
        p1 += __shfl_down(p1, off);
        p2 += __shfl_down(p2, off);
        p3 += __shfl_down(p3, off);
    }
    __shared__ float red[4][4];
    int wv = t >> 6, ln = t & 63;
    if (ln == 0) { red[wv][0]=p0; red[wv][1]=p1; red[wv][2]=p2; red[wv][3]=p3; }
    __syncthreads();
    if (t == 0) {
        float s[4];
        #pragma unroll
        for (int e = 0; e < 4; ++e)
            s[e] = red[0][e]+red[1][e]+red[2][e]+red[3][e] + gb[e];
        int best = 0; float bv = s[0];
        #pragma unroll
        for (int e = 1; e < 4; ++e) if (s[e] > bv) { bv = s[e]; best = e; }  // first-max tie-break
        wgt[tokid] = bv;
        int pos = atomicAdd(&counts[best], 1);
        lists[best*TOK + pos] = tokid;
    }
}

__global__ void zero_counts(int* counts) { if (threadIdx.x < 4) counts[threadIdx.x] = 0; }

// ---------------- final b (h w) c -> b c h w ----------------
__global__ __launch_bounds__(256)
void out_transpose(const float* __restrict__ tok, float* __restrict__ out)
{
    int idx = blockIdx.x*256 + threadIdx.x;   // ((b*768+d)*24+hp)*24+wp
    int wp = idx % 24;
    int hp = (idx / 24) % 24;
    int d  = (idx / 576) % 768;
    int b  = idx / (576*768);
    out[idx] = tok[(size_t)(b*576 + hp*24 + wp)*768 + d];
}

extern "C" void kernel_launch(void* const* d_in, const int* in_sizes, int n_in,
                              void* d_out, int out_size, void* d_ws, size_t ws_size,
                              hipStream_t stream)
{
    const float* x       = (const float*)d_in[0];
    const float* patch_w = (const float*)d_in[1];
    const float* patch_b = (const float*)d_in[2];
    const float* pos     = (const float*)d_in[3];
    const float* ln1_g   = (const float*)d_in[4];
    const float* ln1_b   = (const float*)d_in[5];
    const float* qkv_w   = (const float*)d_in[6];
    const float* qkv_b   = (const float*)d_in[7];
    const float* out_w   = (const float*)d_in[8];
    const float* out_b   = (const float*)d_in[9];
    const float* ln2_g   = (const float*)d_in[10];
    const float* ln2_b   = (const float*)d_in[11];
    const float* gate_w  = (const float*)d_in[12];
    const float* gate_b  = (const float*)d_in[13];
    const float* w1      = (const float*)d_in[14];
    const float* b1      = (const float*)d_in[15];
    const float* w2      = (const float*)d_in[16];
    const float* b2      = (const float*)d_in[17];
    float* out = (float*)d_out;

    // workspace layout (bytes)
    char* wsb = (char*)d_ws;
    size_t OF = 0;
    float*    tok   = (float*)(wsb + OF);    OF += 14155776;   // 4608*768 fp32
    ushort_t* h_h   = (ushort_t*)(wsb + OF); OF += 7077888;    // 4608*768
    ushort_t* h_m   = (ushort_t*)(wsb + OF); OF += 7077888;
    ushort_t* qkvh  = (ushort_t*)(wsb + OF); OF += 21233664;   // 4608*2304
    ushort_t* qkvm  = (ushort_t*)(wsb + OF); OF += 21233664;
    ushort_t* at_h  = (ushort_t*)(wsb + OF); OF += 7077888;    // 4608*768
    ushort_t* at_m  = (ushort_t*)(wsb + OF); OF += 7077888;
    ushort_t* hid_h = (ushort_t*)(wsb + OF); OF += 28311552;   // 4608*3072
    ushort_t* hid_m = (ushort_t*)(wsb + OF); OF += 28311552;
    ushort_t* w_h   = (ushort_t*)(wsb + OF); OF += 42467328;   // 21,233,664 weights/layer
    ushort_t* w_m   = (ushort_t*)(wsb + OF); OF += 42467328;
    float*    wgt   = (float*)(wsb + OF);    OF += 18432;
    int*      lists = (int*)(wsb + OF);      OF += 73728;
    int*      counts= (int*)(wsb + OF);      OF += 16;

    // weight-plane segment offsets (elements)
    const size_t SEG_QKV = 0;
    const size_t SEG_OUT = 1769472;            // 2304*768
    const size_t SEG_W1  = SEG_OUT + 589824;   // 768*768
    const size_t SEG_W2  = SEG_W1  + 9437184;  // 4*3072*768

    // patch embed: im2col limbs (alias hid planes) + patch_w limbs + MFMA GEMM
    im2col_kernel<<<4608, 256, 0, stream>>>(x, hid_h, hid_m);
    cvt_plane<<<192, 256, 0, stream>>>(patch_w, w_h, w_m, 196608);  // 768*256
    gemm_mfma<<<dim3(6,36,1), 256, 0, stream>>>(hid_h, hid_m, w_h, w_m, patch_b,
                                                tok, nullptr, nullptr,
                                                4608, 768, 256, 256, 768, 4,
                                                nullptr, nullptr, pos);

    for (int l = 0; l < 12; ++l) {
        // convert this layer's weights to limb planes (once; GEMMs re-read them 36x)
        cvt_plane<<<1728, 256, 0, stream>>>(qkv_w + (size_t)l*1769472, w_h + SEG_QKV, w_m + SEG_QKV, 1769472);
        cvt_plane<<< 576, 256, 0, stream>>>(out_w + (size_t)l*589824,  w_h + SEG_OUT, w_m + SEG_OUT, 589824);
        cvt_plane<<<9216, 256, 0, stream>>>(w1 + (size_t)l*9437184,    w_h + SEG_W1,  w_m + SEG_W1,  9437184);
        cvt_plane<<<9216, 256, 0, stream>>>(w2 + (size_t)l*9437184,    w_h + SEG_W2,  w_m + SEG_W2,  9437184);

        ln_kernel<<<4608, 256, 0, stream>>>(tok, h_h, h_m, ln1_g + l*768, ln1_b + l*768);
        gemm_mfma<<<dim3(18,36,1), 256, 0, stream>>>(h_h, h_m, w_h + SEG_QKV, w_m + SEG_QKV,
                                                     qkv_b + l*2304, nullptr, qkvh, qkvm,
                                                     4608, 2304, 768, 768, 2304, 0,
                                                     nullptr, nullptr, nullptr);
        attn_kernel<<<dim3(9,12,8), 256, 0, stream>>>(qkvh, qkvm, at_h, at_m);
        gemm_mfma<<<dim3(6,36,1), 256, 0, stream>>>(at_h, at_m, w_h + SEG_OUT, w_m + SEG_OUT,
                                                    out_b + l*768, tok, nullptr, nullptr,
                                                    4608, 768, 768, 768, 768, 1,
                                                    nullptr, nullptr, nullptr);
        ln_kernel<<<4608, 256, 0, stream>>>(tok, h_h, h_m, ln2_g + l*768, ln2_b + l*768);
        zero_counts<<<1, 64, 0, stream>>>(counts);
        gate_kernel<<<4608, 256, 0, stream>>>(h_h, h_m, gate_w + l*3072, gate_b + l*4,
                                              wgt, lists, counts);
        gemm_mfma<<<dim3(24,36,4), 256, 0, stream>>>(h_h, h_m, w_h + SEG_W1, w_m + SEG_W1,
                                                     b1 + (size_t)l*4*3072, nullptr, hid_h, hid_m,
                                                     4608, 3072, 768, 768, 3072, 2,
                                                     lists, counts, nullptr);
        gemm_mfma<<<dim3(6,36,4), 256, 0, stream>>>(hid_h, hid_m, w_h + SEG_W2, w_m + SEG_W2,
                                                    b2 + (size_t)l*4*768, tok, nullptr, nullptr,
                                                    4608, 768, 3072, 3072, 768, 3,
                                                    lists, counts, wgt);
    }
    out_transpose<<<13824, 256, 0, stream>>>(tok, out);
}